// Round 8
// baseline (541.846 us; speedup 1.0000x reference)
//
#include <hip/hip_runtime.h>

// MoE top-2 of 8 experts. T=4096, H=1024, F=4096.
// router -> scan(256-aligned regions) -> gather(x->bf16 + row_map) ->
// register 8x8 W transpose/cvt (no LDS) -> 8-phase grouped GEMM1(relu) ->
// 8-phase grouped GEMM2 (f32 out) -> deterministic combine gather.
#define T_TOK 4096
#define H_DIM 1024
#define F_DIM 4096
#define E_NUM 8
#define R_TOT 8192
#define R_CAP 10240       // 256-aligned regions: worst case 40 tiles = 10240 rows

typedef short bf16x8 __attribute__((ext_vector_type(8)));
typedef float f32x4 __attribute__((ext_vector_type(4)));

__device__ inline unsigned short f2bf(float f) {   // RNE f32 -> bf16
  unsigned int u = __builtin_bit_cast(unsigned int, f);
  return (unsigned short)((u + 0x7FFFu + ((u >> 16) & 1u)) >> 16);
}

__device__ inline void async16(const void* g, void* l) {
  __builtin_amdgcn_global_load_lds((const __attribute__((address_space(1))) void*)g,
                                   (__attribute__((address_space(3))) void*)l, 16, 0, 0);
}

// ---------------- router ------------------------------------------------------
__global__ __launch_bounds__(256) void router_k(
    const float* __restrict__ x, const float* __restrict__ Wr,
    const float* __restrict__ br, int* __restrict__ ctrl,
    int* __restrict__ t2i, float* __restrict__ t2w) {
  int lane = threadIdx.x & 63;
  int wid  = threadIdx.x >> 6;
  int t = blockIdx.x * 4 + wid;
  const float* xr = x + (size_t)t * H_DIM;
  double acc[E_NUM];
#pragma unroll
  for (int e = 0; e < E_NUM; e++) acc[e] = 0.0;
  for (int i = lane; i < H_DIM; i += 64) {
    float xv = xr[i];
    const float* wr = Wr + (size_t)i * E_NUM;
    float4 w0 = *(const float4*)wr;
    float4 w1 = *(const float4*)(wr + 4);
    acc[0] += (double)xv * w0.x; acc[1] += (double)xv * w0.y;
    acc[2] += (double)xv * w0.z; acc[3] += (double)xv * w0.w;
    acc[4] += (double)xv * w1.x; acc[5] += (double)xv * w1.y;
    acc[6] += (double)xv * w1.z; acc[7] += (double)xv * w1.w;
  }
#pragma unroll
  for (int e = 0; e < E_NUM; e++) {
    double v = acc[e];
    for (int off = 32; off > 0; off >>= 1) v += __shfl_down(v, off);
    acc[e] = v;
  }
  if (lane == 0) {
    float l[E_NUM];
#pragma unroll
    for (int e = 0; e < E_NUM; e++) l[e] = (float)acc[e] + br[e];
    int ia = 0; float la = l[0];
#pragma unroll
    for (int e = 1; e < E_NUM; e++) if (l[e] > la) { la = l[e]; ia = e; }
    int ib = -1; float lb = -3.4e38f;
#pragma unroll
    for (int e = 0; e < E_NUM; e++) if (e != ia && l[e] > lb) { lb = l[e]; ib = e; }
    float w0 = 1.f / (1.f + __expf(lb - la));
    float w1 = 1.f - w0;
    t2i[2 * t] = ia; t2i[2 * t + 1] = ib;
    t2w[2 * t] = w0; t2w[2 * t + 1] = w1;
    atomicAdd(&ctrl[ia], 1);
    atomicAdd(&ctrl[ib], 1);
  }
}

// ------- scan: 256-ALIGNED offsets, cursors, row-tile table -------------------
__global__ void scan_k(int* ctrl) {
  if (threadIdx.x != 0) return;
  int off = 0, nt = 0;
  for (int e = 0; e < E_NUM; e++) {
    int c = ctrl[e];
    ctrl[8 + e]  = off;
    ctrl[17 + e] = off;
    int tiles = (c + 255) >> 8;
    for (int j = 0; j < tiles; j++) {
      ctrl[32 + 2 * nt] = e;
      ctrl[33 + 2 * nt] = off + j * 256;
      nt++;
    }
    off += tiles * 256;
  }
  ctrl[16] = off;
  ctrl[25] = nt;
}

// ---------------- gather: x row -> bf16 row; row_map[token*2+slot] = row ------
__global__ __launch_bounds__(128) void gather_k(
    const float* __restrict__ x, const int* __restrict__ t2i,
    int* __restrict__ ctrl, int* __restrict__ row_map,
    unsigned short* __restrict__ xg) {
  int bid = blockIdx.x;
  __shared__ int srow;
  if (threadIdx.x == 0) {
    int e = t2i[bid];
    int row = atomicAdd(&ctrl[17 + e], 1);
    row_map[bid] = row;
    srow = row;
  }
  __syncthreads();
  int row = srow;
  int t = bid >> 1;
  const float* src = x + (size_t)t * H_DIM + threadIdx.x * 8;
  unsigned short* dst = xg + (size_t)row * H_DIM + threadIdx.x * 8;
  float4 v0 = *(const float4*)src;
  float4 v1 = *(const float4*)(src + 4);
  uint4 o;
  o.x = (unsigned int)f2bf(v0.x) | ((unsigned int)f2bf(v0.y) << 16);
  o.y = (unsigned int)f2bf(v0.z) | ((unsigned int)f2bf(v0.w) << 16);
  o.z = (unsigned int)f2bf(v1.x) | ((unsigned int)f2bf(v1.y) << 16);
  o.w = (unsigned int)f2bf(v1.z) | ((unsigned int)f2bf(v1.w) << 16);
  *(uint4*)dst = o;
}

// ------- register 8x8 transpose + fp32->bf16 (no LDS): in[R][C] -> out[C][R] --
// Block = 64 rows x 256 cols. Thread owns an 8x8 micro-tile:
//   r0 = by*64 + (tid&7)*8, c0 = bx*256 + (tid>>3)*8.
// Loads: 16 float4; per inst 8 lanes (same tid&7) read 16B at 32B stride -- the
// two halves of each row-pair cover full lines. Stores: 8 uint4; per inst the 8
// lanes with tid&7=0..7 write 16B each -> 128B contiguous per output row. Fully
// coalesced both sides, zero LDS.
__global__ __launch_bounds__(256) void tconv_k(
    const float* __restrict__ in, unsigned short* __restrict__ out, int R, int C) {
  size_t mat = (size_t)R * C;
  const float* ip = in + (size_t)blockIdx.z * mat;
  unsigned short* op = out + (size_t)blockIdx.z * mat;
  int r0 = blockIdx.y * 64 + (threadIdx.x & 7) * 8;
  int c0 = blockIdx.x * 256 + (threadIdx.x >> 3) * 8;
  const float* src = ip + (size_t)r0 * C + c0;
  float va[8][8];
#pragma unroll
  for (int i = 0; i < 8; i++) {
    float4 a = *(const float4*)(src + (size_t)i * C);
    float4 b = *(const float4*)(src + (size_t)i * C + 4);
    va[i][0] = a.x; va[i][1] = a.y; va[i][2] = a.z; va[i][3] = a.w;
    va[i][4] = b.x; va[i][5] = b.y; va[i][6] = b.z; va[i][7] = b.w;
  }
#pragma unroll
  for (int j = 0; j < 8; j++) {
    uint4 o;
    o.x = (unsigned int)f2bf(va[0][j]) | ((unsigned int)f2bf(va[1][j]) << 16);
    o.y = (unsigned int)f2bf(va[2][j]) | ((unsigned int)f2bf(va[3][j]) << 16);
    o.z = (unsigned int)f2bf(va[4][j]) | ((unsigned int)f2bf(va[5][j]) << 16);
    o.w = (unsigned int)f2bf(va[6][j]) | ((unsigned int)f2bf(va[7][j]) << 16);
    *(uint4*)(op + (size_t)(c0 + j) * R + r0) = o;
  }
}

// =============== 8-phase grouped BT GEMM, 256x256 tile, BK=64, 8 waves ========
// LDS: row-major [256][64] bf16, XOR-swizzled 16B k-octets:
// unit(16B) = row*8 + (koct ^ (row&7)).  Staging dest linear in tid; global
// source pre-swizzled within each row's 128B line (coalesced).  vmcnt(10)
// end-p1, vmcnt(8) end-p3, never 0.  sched_barrier fences pin the skeleton
// (r4/r5 A/B: load-bearing).  Blocks XCD-chunked + supertiled.
#define BAR() do { __builtin_amdgcn_sched_barrier(0); \
                   __builtin_amdgcn_s_barrier(); \
                   __builtin_amdgcn_sched_barrier(0); } while (0)

#define STG(gbase, kt, lbuf, c) \
  async16((gbase) + (size_t)((c) * 64 + srcRow) * Kstr + (kt) + srcK8, \
          (lbuf) + (c) * 4096 + tid * 8)

#define LDU(buf, row, koct) \
  (*(const bf16x8*)((buf) + (((row) * 8 + ((koct) ^ ((row) & 7))) * 8)))

#define LDA4(P) \
  const int ar0 = wm * 128 + (P) * 32 + lr; \
  bf16x8 aA = LDU(lAc, ar0, klane); \
  bf16x8 aB = LDU(lAc, ar0, 4 + klane); \
  bf16x8 aC = LDU(lAc, ar0 + 16, klane); \
  bf16x8 aD = LDU(lAc, ar0 + 16, 4 + klane);

#define PHASE_MFMA(M0, M1) \
  __builtin_amdgcn_s_setprio(1); \
  _Pragma("unroll") \
  for (int n = 0; n < 4; n++) { \
    acc[M0][n] = __builtin_amdgcn_mfma_f32_16x16x32_bf16(aA, b[n][0], acc[M0][n], 0, 0, 0); \
    acc[M0][n] = __builtin_amdgcn_mfma_f32_16x16x32_bf16(aB, b[n][1], acc[M0][n], 0, 0, 0); \
    acc[M1][n] = __builtin_amdgcn_mfma_f32_16x16x32_bf16(aC, b[n][0], acc[M1][n], 0, 0, 0); \
    acc[M1][n] = __builtin_amdgcn_mfma_f32_16x16x32_bf16(aD, b[n][1], acc[M1][n], 0, 0, 0); \
  } \
  __builtin_amdgcn_s_setprio(0);

template <bool RELU, bool OUTF32>
__global__ __launch_bounds__(512, 2) void gemm8_k(
    const int* __restrict__ ctrl, const unsigned short* __restrict__ A,
    const unsigned short* __restrict__ Bw, const float* __restrict__ bias,
    void* __restrict__ Cout, int Kstr, int N) {
  __shared__ unsigned short lds[65536];   // 128 KiB: A 2x32KB | B 2x32KB
  // ---- block mapping: XCD chunk (nwg%8==0: 640 or 160) then supertile ----
  const int nx = gridDim.x;
  const int nwg = nx * (int)gridDim.y;
  const int lin = blockIdx.y * nx + blockIdx.x;
  const int q = nwg >> 3;
  const int wg = (lin & 7) * q + (lin >> 3);
  int rt, bx;
  if (nx == 16) {           // GEMM1: 4rt x 4bx supertiles
    int st = wg >> 4, cell = wg & 15;
    rt = (st >> 2) * 4 + (cell >> 2);
    bx = (st & 3) * 4 + (cell & 3);
  } else {                  // GEMM2 (nx=4): 2rt x 4bx supertiles
    int st = wg >> 3, cell = wg & 7;
    rt = st * 2 + (cell >> 2);
    bx = cell & 3;
  }
  if (rt >= ctrl[25]) return;
  const int e    = ctrl[32 + 2 * rt];
  const int row0 = ctrl[33 + 2 * rt];
  const unsigned short* Ae = A + (size_t)row0 * Kstr;
  const unsigned short* Be = Bw + (size_t)e * ((size_t)N * Kstr) + (size_t)bx * 256 * Kstr;
  unsigned short* lA = lds;
  unsigned short* lB = lds + 32768;
  const int tid = threadIdx.x, lane = tid & 63;
  const int wid = tid >> 6, wm = wid >> 2, wn = wid & 3;
  const int lr = lane & 15, klane = lane >> 4;
  const int srcRow = tid >> 3;                         // 0..63 within chunk
  const int srcK8  = ((tid & 7) ^ (srcRow & 7)) * 8;   // pre-swizzled k-octet
  const int NT = Kstr >> 6;

  f32x4 acc[8][4];
  f32x4 zero4 = {0.f, 0.f, 0.f, 0.f};
#pragma unroll
  for (int m = 0; m < 8; m++)
#pragma unroll
    for (int n = 0; n < 4; n++) acc[m][n] = zero4;

  // prologue: tile0 full (8), tile1 partial (B0-3, A0, A2)
  {
    STG(Ae, 0, lA, 0); STG(Ae, 0, lA, 1); STG(Ae, 0, lA, 2); STG(Ae, 0, lA, 3);
    STG(Be, 0, lB, 0); STG(Be, 0, lB, 1); STG(Be, 0, lB, 2); STG(Be, 0, lB, 3);
    STG(Be, 64, lB + 16384, 0); STG(Be, 64, lB + 16384, 1);
    STG(Be, 64, lB + 16384, 2); STG(Be, 64, lB + 16384, 3);
    STG(Ae, 64, lA + 16384, 0); STG(Ae, 64, lA + 16384, 2);
    asm volatile("s_waitcnt vmcnt(6)" ::: "memory");
    BAR();
  }

  for (int t = 0; t < NT; t++) {
    const int cur = t & 1;
    unsigned short* lAc = lA + cur * 16384;
    unsigned short* lBc = lB + cur * 16384;
    unsigned short* lAn = lA + (cur ^ 1) * 16384;
    const int kt1 = min(t + 1, NT - 1) * 64;
    const int kt2 = min(t + 2, NT - 1) * 64;
    bf16x8 b[4][2];
    { // ---- phase 0: read B whole + A rows 0-31; stage A chunks 1,3 of t+1
#pragma unroll
      for (int n = 0; n < 4; n++) {
        int brow = wn * 64 + n * 16 + lr;
        b[n][0] = LDU(lBc, brow, klane);
        b[n][1] = LDU(lBc, brow, 4 + klane);
      }
      LDA4(0)
      STG(Ae, kt1, lAn, 1); STG(Ae, kt1, lAn, 3);
      BAR();
      PHASE_MFMA(0, 1)
      BAR();
    }
    { // ---- phase 1: A rows 32-63; stage B chunks 0,1 of t+2; vmcnt(10)
      LDA4(1)
      STG(Be, kt2, lBc, 0); STG(Be, kt2, lBc, 1);
      BAR();
      PHASE_MFMA(2, 3)
      asm volatile("s_waitcnt vmcnt(10)" ::: "memory");
      BAR();
    }
    { // ---- phase 2: A rows 64-95; stage B chunks 2,3 of t+2
      LDA4(2)
      STG(Be, kt2, lBc, 2); STG(Be, kt2, lBc, 3);
      BAR();
      PHASE_MFMA(4, 5)
      BAR();
    }
    { // ---- phase 3: A rows 96-127; stage A chunks 0,2 of t+2; vmcnt(8)
      LDA4(3)
      STG(Ae, kt2, lAc, 0); STG(Ae, kt2, lAc, 2);
      BAR();
      PHASE_MFMA(6, 7)
      asm volatile("s_waitcnt vmcnt(8)" ::: "memory");
      BAR();
    }
  }

  // ---------------- epilogue: plain stores, no atomics -------------------------
  const int n0 = bx * 256;
  const float* be = bias + (size_t)e * N;
#pragma unroll
  for (int m = 0; m < 8; m++) {
#pragma unroll
    for (int q2 = 0; q2 < 4; q2++) {
      size_t ro = (size_t)(row0 + wm * 128 + m * 16 + (lane >> 4) * 4 + q2) * N;
#pragma unroll
      for (int n = 0; n < 4; n++) {
        int col = n0 + wn * 64 + n * 16 + lr;
        float v = acc[m][n][q2] + be[col];
        if (RELU) v = fmaxf(v, 0.f);
        if (OUTF32) ((float*)Cout)[ro + col] = v;
        else ((unsigned short*)Cout)[ro + col] = f2bf(v);
      }
    }
  }
}

// ---------------- combine: out[t] = w0*y[r0] + w1*y[r1] ----------------------
__global__ __launch_bounds__(256) void combine_k(
    const float* __restrict__ y, const int* __restrict__ row_map,
    const float* __restrict__ t2w, float* __restrict__ out) {
  int t = blockIdx.x;
  int i = threadIdx.x * 4;
  int r0 = row_map[2 * t], r1 = row_map[2 * t + 1];
  float w0 = t2w[2 * t], w1 = t2w[2 * t + 1];
  float4 a = *(const float4*)(y + (size_t)r0 * H_DIM + i);
  float4 b = *(const float4*)(y + (size_t)r1 * H_DIM + i);
  float4 o;
  o.x = w0 * a.x + w1 * b.x;
  o.y = w0 * a.y + w1 * b.y;
  o.z = w0 * a.z + w1 * b.z;
  o.w = w0 * a.w + w1 * b.w;
  *(float4*)(out + (size_t)t * H_DIM + i) = o;
}

extern "C" void kernel_launch(void* const* d_in, const int* in_sizes, int n_in,
                              void* d_out, int out_size, void* d_ws, size_t ws_size,
                              hipStream_t stream) {
  const float* x  = (const float*)d_in[0];
  const float* Wr = (const float*)d_in[1];
  const float* br = (const float*)d_in[2];
  const float* W1 = (const float*)d_in[3];
  const float* b1 = (const float*)d_in[4];
  const float* W2 = (const float*)d_in[5];
  const float* b2 = (const float*)d_in[6];
  float* out = (float*)d_out;

  char* ws = (char*)d_ws;
  int*   ctrl    = (int*)ws;                       // counts/offs/cursors/tile table
  int*   t2i     = (int*)(ws + 4096);
  float* t2w     = (float*)(ws + 4096 + 32768);
  int*   row_map = (int*)(ws + 4096 + 65536);      // R_TOT ints
  size_t off = (size_t)1 << 20;
  unsigned short* WT1 = (unsigned short*)(ws + off); off += (size_t)E_NUM * F_DIM * H_DIM * 2;
  unsigned short* WT2 = (unsigned short*)(ws + off); off += (size_t)E_NUM * H_DIM * F_DIM * 2;
  unsigned short* xg  = (unsigned short*)(ws + off); off += (size_t)R_CAP * H_DIM * 2;
  unsigned short* hb  = (unsigned short*)(ws + off); off += (size_t)R_CAP * F_DIM * 2;
  float*          yb  = (float*)(ws + off);          off += (size_t)R_CAP * H_DIM * 4;

  if (ws_size < off) {  // not enough scratch: fail visibly, don't corrupt memory
    hipMemsetAsync(d_out, 0, (size_t)out_size * 4, stream);
    return;
  }

  hipMemsetAsync(ctrl, 0, 4096, stream);
  hipMemsetAsync(xg, 0, (size_t)R_CAP * H_DIM * 2, stream);   // pad rows deterministic
  // W1[H][F] -> WT1[F][H]; W2[F][H] -> WT2[H][F]  (register 8x8, exact grids)
  tconv_k<<<dim3(F_DIM / 256, H_DIM / 64, E_NUM), 256, 0, stream>>>(W1, WT1, H_DIM, F_DIM);
  tconv_k<<<dim3(H_DIM / 256, F_DIM / 64, E_NUM), 256, 0, stream>>>(W2, WT2, F_DIM, H_DIM);
  router_k<<<dim3(T_TOK / 4), 256, 0, stream>>>(x, Wr, br, ctrl, t2i, t2w);
  scan_k<<<dim3(1), 64, 0, stream>>>(ctrl);
  gather_k<<<dim3(R_TOT), 128, 0, stream>>>(x, t2i, ctrl, row_map, xg);
  // GEMM1: hb = relu(xg @ W1 + b1), bf16   [rows x F]
  gemm8_k<true, false><<<dim3(F_DIM / 256, 40), 512, 0, stream>>>(
      ctrl, xg, WT1, b1, hb, H_DIM, F_DIM);
  // GEMM2: yb = hb @ W2 + b2, fp32         [rows x H]
  gemm8_k<false, true><<<dim3(H_DIM / 256, 40), 512, 0, stream>>>(
      ctrl, hb, WT2, b2, yb, F_DIM, H_DIM);
  combine_k<<<dim3(T_TOK), 256, 0, stream>>>(yb, row_map, t2w, out);
}

// Round 10
// 500.463 us; speedup vs baseline: 1.0827x; 1.0827x over previous
//
#include <hip/hip_runtime.h>

// MoE top-2 of 8 experts. T=4096, H=1024, F=4096.
// router -> wave-parallel scan(256-aligned regions) -> gather(x->bf16+row_map)
// -> merged exact-grid W transpose/cvt -> 8-phase grouped GEMM1(relu) ->
// 8-phase grouped GEMM2 (f32 out) -> combine gather.
// GEMM blocks XCD-pinned: per-XCD B-columns so B panels stay L2-resident.
#define T_TOK 4096
#define H_DIM 1024
#define F_DIM 4096
#define E_NUM 8
#define R_TOT 8192
#define R_CAP 10240       // 256-aligned regions: worst case 40 tiles

typedef short bf16x8 __attribute__((ext_vector_type(8)));
typedef float f32x4 __attribute__((ext_vector_type(4)));

__device__ inline unsigned short f2bf(float f) {   // RNE f32 -> bf16
  unsigned int u = __builtin_bit_cast(unsigned int, f);
  return (unsigned short)((u + 0x7FFFu + ((u >> 16) & 1u)) >> 16);
}

__device__ inline void async16(const void* g, void* l) {
  __builtin_amdgcn_global_load_lds((const __attribute__((address_space(1))) void*)g,
                                   (__attribute__((address_space(3))) void*)l, 16, 0, 0);
}

// ---------------- router ------------------------------------------------------
__global__ __launch_bounds__(256) void router_k(
    const float* __restrict__ x, const float* __restrict__ Wr,
    const float* __restrict__ br, int* __restrict__ ctrl,
    int* __restrict__ t2i, float* __restrict__ t2w) {
  int lane = threadIdx.x & 63;
  int wid  = threadIdx.x >> 6;
  int t = blockIdx.x * 4 + wid;
  const float* xr = x + (size_t)t * H_DIM;
  double acc[E_NUM];
#pragma unroll
  for (int e = 0; e < E_NUM; e++) acc[e] = 0.0;
  for (int i = lane; i < H_DIM; i += 64) {
    float xv = xr[i];
    const float* wr = Wr + (size_t)i * E_NUM;
    float4 w0 = *(const float4*)wr;
    float4 w1 = *(const float4*)(wr + 4);
    acc[0] += (double)xv * w0.x; acc[1] += (double)xv * w0.y;
    acc[2] += (double)xv * w0.z; acc[3] += (double)xv * w0.w;
    acc[4] += (double)xv * w1.x; acc[5] += (double)xv * w1.y;
    acc[6] += (double)xv * w1.z; acc[7] += (double)xv * w1.w;
  }
#pragma unroll
  for (int e = 0; e < E_NUM; e++) {
    double v = acc[e];
    for (int off = 32; off > 0; off >>= 1) v += __shfl_down(v, off);
    acc[e] = v;
  }
  if (lane == 0) {
    float l[E_NUM];
#pragma unroll
    for (int e = 0; e < E_NUM; e++) l[e] = (float)acc[e] + br[e];
    int ia = 0; float la = l[0];
#pragma unroll
    for (int e = 1; e < E_NUM; e++) if (l[e] > la) { la = l[e]; ia = e; }
    int ib = -1; float lb = -3.4e38f;
#pragma unroll
    for (int e = 0; e < E_NUM; e++) if (e != ia && l[e] > lb) { lb = l[e]; ib = e; }
    float w0 = 1.f / (1.f + __expf(lb - la));
    float w1 = 1.f - w0;
    t2i[2 * t] = ia; t2i[2 * t + 1] = ib;
    t2w[2 * t] = w0; t2w[2 * t + 1] = w1;
    atomicAdd(&ctrl[ia], 1);
    atomicAdd(&ctrl[ib], 1);
  }
}

// ------- scan (1 wave): 256-aligned offsets + tile table, shfl prefix ---------
// Regions packed 256-aligned => tile i starts at row i*256; only its expert id
// needs lookup.
__global__ void scan_k(int* ctrl) {
  int lane = threadIdx.x;     // 64 threads
  int c = (lane < 8) ? ctrl[lane] : 0;
  int tiles = (c + 255) >> 8;
  int x = tiles;
  for (int d = 1; d < 8; d <<= 1) {   // inclusive prefix over lanes 0..7
    int y = __shfl_up(x, d);
    if (lane >= d) x += y;
  }
  int excl = x - tiles;
  if (lane < 8) {
    ctrl[8 + lane]  = excl * 256;
    ctrl[17 + lane] = excl * 256;
  }
  int tot = __shfl(x, 7);
  if (lane == 0) { ctrl[25] = tot; ctrl[16] = tot * 256; }
  int myE = -1;
#pragma unroll
  for (int e = 0; e < 8; e++) {
    int ex = __shfl(excl, e), tl = __shfl(tiles, e);
    if (lane >= ex && lane < ex + tl) myE = e;
  }
  if (lane < tot) {
    ctrl[32 + 2 * lane] = myE;
    ctrl[33 + 2 * lane] = lane * 256;
  }
}

// ---------------- gather: x row -> bf16 row; row_map[token*2+slot] = row ------
__global__ __launch_bounds__(128) void gather_k(
    const float* __restrict__ x, const int* __restrict__ t2i,
    int* __restrict__ ctrl, int* __restrict__ row_map,
    unsigned short* __restrict__ xg) {
  int bid = blockIdx.x;
  __shared__ int srow;
  if (threadIdx.x == 0) {
    int e = t2i[bid];
    int row = atomicAdd(&ctrl[17 + e], 1);
    row_map[bid] = row;
    srow = row;
  }
  __syncthreads();
  int row = srow;
  int t = bid >> 1;
  const float* src = x + (size_t)t * H_DIM + threadIdx.x * 8;
  unsigned short* dst = xg + (size_t)row * H_DIM + threadIdx.x * 8;
  float4 v0 = *(const float4*)src;
  float4 v1 = *(const float4*)(src + 4);
  uint4 o;
  o.x = (unsigned int)f2bf(v0.x) | ((unsigned int)f2bf(v0.y) << 16);
  o.y = (unsigned int)f2bf(v0.z) | ((unsigned int)f2bf(v0.w) << 16);
  o.z = (unsigned int)f2bf(v1.x) | ((unsigned int)f2bf(v1.y) << 16);
  o.w = (unsigned int)f2bf(v1.z) | ((unsigned int)f2bf(v1.w) << 16);
  *(uint4*)dst = o;
}

// ------- merged transpose + fp32->bf16, exact flat grid (16384 blocks) --------
// Each matrix is 1024x4096 (4M elems) = 1024 tiles of 64x64 per expert.
// bid<8192: W1 expert e=bid>>10 (R=H=1024,C=F=4096): t=bid&1023, bx=t&63, by=t>>6.
// else:     W2 expert        (R=F=4096,C=H=1024):             bx=t&15, by=t>>4.
// fp32 tile[64][65]: 2-way banks both passes (verified mod-32 arithmetic).
__global__ __launch_bounds__(256) void tconv_k(
    const float* __restrict__ W1, const float* __restrict__ W2,
    unsigned short* __restrict__ WT1, unsigned short* __restrict__ WT2) {
  size_t mat = (size_t)H_DIM * F_DIM;
  int bid = blockIdx.x;
  const float* in; unsigned short* out; int R, C, bx, by;
  if (bid < 8192) {
    int e = bid >> 10, t = bid & 1023;
    in = W1 + e * mat; out = WT1 + e * mat; R = H_DIM; C = F_DIM;
    bx = t & 63; by = t >> 6;
  } else {
    int e = (bid - 8192) >> 10, t = bid & 1023;
    in = W2 + e * mat; out = WT2 + e * mat; R = F_DIM; C = H_DIM;
    bx = t & 15; by = t >> 4;
  }
  int c0 = bx * 64, r0 = by * 64;
  __shared__ float tile[64][65];
  int tr = threadIdx.x >> 4, tc = threadIdx.x & 15;
#pragma unroll
  for (int p = 0; p < 4; p++) {
    int r = tr + p * 16;
    float4 v = *(const float4*)(in + (size_t)(r0 + r) * C + c0 + tc * 4);
    tile[r][tc * 4 + 0] = v.x; tile[r][tc * 4 + 1] = v.y;
    tile[r][tc * 4 + 2] = v.z; tile[r][tc * 4 + 3] = v.w;
  }
  __syncthreads();
  int cc = threadIdx.x >> 3;        // 0..31
  int r8 = (threadIdx.x & 7) * 8;   // 0..56
#pragma unroll
  for (int p = 0; p < 2; p++) {
    int c = cc + p * 32;
    uint4 o;
    o.x = (unsigned int)f2bf(tile[r8 + 0][c]) | ((unsigned int)f2bf(tile[r8 + 1][c]) << 16);
    o.y = (unsigned int)f2bf(tile[r8 + 2][c]) | ((unsigned int)f2bf(tile[r8 + 3][c]) << 16);
    o.z = (unsigned int)f2bf(tile[r8 + 4][c]) | ((unsigned int)f2bf(tile[r8 + 5][c]) << 16);
    o.w = (unsigned int)f2bf(tile[r8 + 6][c]) | ((unsigned int)f2bf(tile[r8 + 7][c]) << 16);
    *(uint4*)(out + (size_t)(c0 + c) * R + r0 + r8) = o;
  }
}

// =============== 8-phase grouped BT GEMM, 256x256 tile, BK=64, 8 waves ========
// LDS: row-major [256][64] bf16, XOR-swizzled 16B k-octets:
// unit(16B) = row*8 + (koct ^ (row&7)).  vmcnt(10) end-p1, vmcnt(8) end-p3.
// sched_barrier fences pin the skeleton (r4/r5 A/B: load-bearing).
// Block mapping (MAP): XCD-pinned bx so B panels are L2-resident:
//  MAP=1 (GEMM1, 640 blocks): xcd=bid&7 owns bx {2*xcd, 2*xcd+1};
//        s=bid>>3: rt=s>>1, bx=xcd*2+(s&1)  (rt pair adjacent => A L2-shared)
//  MAP=2 (GEMM2, 160 blocks): xcd=bid&7: bx=xcd>>1, rt=(xcd&1)*20 + (bid>>3)
#define BAR() do { __builtin_amdgcn_sched_barrier(0); \
                   __builtin_amdgcn_s_barrier(); \
                   __builtin_amdgcn_sched_barrier(0); } while (0)

#define STG(gbase, kt, lbuf, c) \
  async16((gbase) + (size_t)((c) * 64 + srcRow) * Kstr + (kt) + srcK8, \
          (lbuf) + (c) * 4096 + tid * 8)

#define LDU(buf, row, koct) \
  (*(const bf16x8*)((buf) + (((row) * 8 + ((koct) ^ ((row) & 7))) * 8)))

#define LDA4(P) \
  const int ar0 = wm * 128 + (P) * 32 + lr; \
  bf16x8 aA = LDU(lAc, ar0, klane); \
  bf16x8 aB = LDU(lAc, ar0, 4 + klane); \
  bf16x8 aC = LDU(lAc, ar0 + 16, klane); \
  bf16x8 aD = LDU(lAc, ar0 + 16, 4 + klane);

#define PHASE_MFMA(M0, M1) \
  __builtin_amdgcn_s_setprio(1); \
  _Pragma("unroll") \
  for (int n = 0; n < 4; n++) { \
    acc[M0][n] = __builtin_amdgcn_mfma_f32_16x16x32_bf16(aA, b[n][0], acc[M0][n], 0, 0, 0); \
    acc[M0][n] = __builtin_amdgcn_mfma_f32_16x16x32_bf16(aB, b[n][1], acc[M0][n], 0, 0, 0); \
    acc[M1][n] = __builtin_amdgcn_mfma_f32_16x16x32_bf16(aC, b[n][0], acc[M1][n], 0, 0, 0); \
    acc[M1][n] = __builtin_amdgcn_mfma_f32_16x16x32_bf16(aD, b[n][1], acc[M1][n], 0, 0, 0); \
  } \
  __builtin_amdgcn_s_setprio(0);

template <int MAP, bool RELU, bool OUTF32>
__global__ __launch_bounds__(512, 2) void gemm8_k(
    const int* __restrict__ ctrl, const unsigned short* __restrict__ A,
    const unsigned short* __restrict__ Bw, const float* __restrict__ bias,
    void* __restrict__ Cout, int Kstr, int N) {
  __shared__ unsigned short lds[65536];   // 128 KiB: A 2x32KB | B 2x32KB
  const int bid = blockIdx.x;
  int rt, bx;
  if (MAP == 1) { int xcd = bid & 7, s = bid >> 3; rt = s >> 1; bx = xcd * 2 + (s & 1); }
  else          { int xcd = bid & 7, s = bid >> 3; bx = xcd >> 1; rt = (xcd & 1) * 20 + s; }
  if (rt >= ctrl[25]) return;
  const int e    = ctrl[32 + 2 * rt];
  const int row0 = ctrl[33 + 2 * rt];
  const unsigned short* Ae = A + (size_t)row0 * Kstr;
  const unsigned short* Be = Bw + (size_t)e * ((size_t)N * Kstr) + (size_t)bx * 256 * Kstr;
  unsigned short* lA = lds;
  unsigned short* lB = lds + 32768;
  const int tid = threadIdx.x, lane = tid & 63;
  const int wid = tid >> 6, wm = wid >> 2, wn = wid & 3;
  const int lr = lane & 15, klane = lane >> 4;
  const int srcRow = tid >> 3;                         // 0..63 within chunk
  const int srcK8  = ((tid & 7) ^ (srcRow & 7)) * 8;   // pre-swizzled k-octet
  const int NT = Kstr >> 6;

  f32x4 acc[8][4];
  f32x4 zero4 = {0.f, 0.f, 0.f, 0.f};
#pragma unroll
  for (int m = 0; m < 8; m++)
#pragma unroll
    for (int n = 0; n < 4; n++) acc[m][n] = zero4;

  // prologue: tile0 full (8), tile1 partial (B0-3, A0, A2)
  {
    STG(Ae, 0, lA, 0); STG(Ae, 0, lA, 1); STG(Ae, 0, lA, 2); STG(Ae, 0, lA, 3);
    STG(Be, 0, lB, 0); STG(Be, 0, lB, 1); STG(Be, 0, lB, 2); STG(Be, 0, lB, 3);
    STG(Be, 64, lB + 16384, 0); STG(Be, 64, lB + 16384, 1);
    STG(Be, 64, lB + 16384, 2); STG(Be, 64, lB + 16384, 3);
    STG(Ae, 64, lA + 16384, 0); STG(Ae, 64, lA + 16384, 2);
    asm volatile("s_waitcnt vmcnt(6)" ::: "memory");
    BAR();
  }

  for (int t = 0; t < NT; t++) {
    const int cur = t & 1;
    unsigned short* lAc = lA + cur * 16384;
    unsigned short* lBc = lB + cur * 16384;
    unsigned short* lAn = lA + (cur ^ 1) * 16384;
    const int kt1 = min(t + 1, NT - 1) * 64;
    const int kt2 = min(t + 2, NT - 1) * 64;
    bf16x8 b[4][2];
    { // ---- phase 0: read B whole + A rows 0-31; stage A chunks 1,3 of t+1
#pragma unroll
      for (int n = 0; n < 4; n++) {
        int brow = wn * 64 + n * 16 + lr;
        b[n][0] = LDU(lBc, brow, klane);
        b[n][1] = LDU(lBc, brow, 4 + klane);
      }
      LDA4(0)
      STG(Ae, kt1, lAn, 1); STG(Ae, kt1, lAn, 3);
      BAR();
      PHASE_MFMA(0, 1)
      BAR();
    }
    { // ---- phase 1: A rows 32-63; stage B chunks 0,1 of t+2; vmcnt(10)
      LDA4(1)
      STG(Be, kt2, lBc, 0); STG(Be, kt2, lBc, 1);
      BAR();
      PHASE_MFMA(2, 3)
      asm volatile("s_waitcnt vmcnt(10)" ::: "memory");
      BAR();
    }
    { // ---- phase 2: A rows 64-95; stage B chunks 2,3 of t+2
      LDA4(2)
      STG(Be, kt2, lBc, 2); STG(Be, kt2, lBc, 3);
      BAR();
      PHASE_MFMA(4, 5)
      BAR();
    }
    { // ---- phase 3: A rows 96-127; stage A chunks 0,2 of t+2; vmcnt(8)
      LDA4(3)
      STG(Ae, kt2, lAc, 0); STG(Ae, kt2, lAc, 2);
      BAR();
      PHASE_MFMA(6, 7)
      asm volatile("s_waitcnt vmcnt(8)" ::: "memory");
      BAR();
    }
  }

  // ---------------- epilogue: plain stores, no atomics -------------------------
  const int n0 = bx * 256;
  const float* be = bias + (size_t)e * N;
#pragma unroll
  for (int m = 0; m < 8; m++) {
#pragma unroll
    for (int q2 = 0; q2 < 4; q2++) {
      size_t ro = (size_t)(row0 + wm * 128 + m * 16 + (lane >> 4) * 4 + q2) * N;
#pragma unroll
      for (int n = 0; n < 4; n++) {
        int col = n0 + wn * 64 + n * 16 + lr;
        float v = acc[m][n][q2] + be[col];
        if (RELU) v = fmaxf(v, 0.f);
        if (OUTF32) ((float*)Cout)[ro + col] = v;
        else ((unsigned short*)Cout)[ro + col] = f2bf(v);
      }
    }
  }
}

// ---------------- combine: out[t] = w0*y[r0] + w1*y[r1] ----------------------
__global__ __launch_bounds__(256) void combine_k(
    const float* __restrict__ y, const int* __restrict__ row_map,
    const float* __restrict__ t2w, float* __restrict__ out) {
  int t = blockIdx.x;
  int i = threadIdx.x * 4;
  int r0 = row_map[2 * t], r1 = row_map[2 * t + 1];
  float w0 = t2w[2 * t], w1 = t2w[2 * t + 1];
  float4 a = *(const float4*)(y + (size_t)r0 * H_DIM + i);
  float4 b = *(const float4*)(y + (size_t)r1 * H_DIM + i);
  float4 o;
  o.x = w0 * a.x + w1 * b.x;
  o.y = w0 * a.y + w1 * b.y;
  o.z = w0 * a.z + w1 * b.z;
  o.w = w0 * a.w + w1 * b.w;
  *(float4*)(out + (size_t)t * H_DIM + i) = o;
}

extern "C" void kernel_launch(void* const* d_in, const int* in_sizes, int n_in,
                              void* d_out, int out_size, void* d_ws, size_t ws_size,
                              hipStream_t stream) {
  const float* x  = (const float*)d_in[0];
  const float* Wr = (const float*)d_in[1];
  const float* br = (const float*)d_in[2];
  const float* W1 = (const float*)d_in[3];
  const float* b1 = (const float*)d_in[4];
  const float* W2 = (const float*)d_in[5];
  const float* b2 = (const float*)d_in[6];
  float* out = (float*)d_out;

  char* ws = (char*)d_ws;
  int*   ctrl    = (int*)ws;                       // counts/offs/cursors/tile table
  int*   t2i     = (int*)(ws + 4096);
  float* t2w     = (float*)(ws + 4096 + 32768);
  int*   row_map = (int*)(ws + 4096 + 65536);      // R_TOT ints
  size_t off = (size_t)1 << 20;
  unsigned short* WT1 = (unsigned short*)(ws + off); off += (size_t)E_NUM * F_DIM * H_DIM * 2;
  unsigned short* WT2 = (unsigned short*)(ws + off); off += (size_t)E_NUM * H_DIM * F_DIM * 2;
  unsigned short* xg  = (unsigned short*)(ws + off); off += (size_t)R_CAP * H_DIM * 2;
  unsigned short* hb  = (unsigned short*)(ws + off); off += (size_t)R_CAP * F_DIM * 2;
  float*          yb  = (float*)(ws + off);          off += (size_t)R_CAP * H_DIM * 4;

  if (ws_size < off) {  // not enough scratch: fail visibly, don't corrupt memory
    hipMemsetAsync(d_out, 0, (size_t)out_size * 4, stream);
    return;
  }

  hipMemsetAsync(ctrl, 0, 4096, stream);
  hipMemsetAsync(xg, 0, (size_t)R_CAP * H_DIM * 2, stream);   // pad rows deterministic
  tconv_k<<<dim3(16384), 256, 0, stream>>>(W1, W2, WT1, WT2);
  router_k<<<dim3(T_TOK / 4), 256, 0, stream>>>(x, Wr, br, ctrl, t2i, t2w);
  scan_k<<<dim3(1), 64, 0, stream>>>(ctrl);
  gather_k<<<dim3(R_TOT), 128, 0, stream>>>(x, t2i, ctrl, row_map, xg);
  // GEMM1: hb = relu(xg @ W1 + b1), bf16   [rows x F]   640 blocks XCD-pinned
  gemm8_k<1, true, false><<<dim3(640), 512, 0, stream>>>(
      ctrl, xg, WT1, b1, hb, H_DIM, F_DIM);
  // GEMM2: yb = hb @ W2 + b2, fp32         [rows x H]   160 blocks XCD-pinned
  gemm8_k<2, false, true><<<dim3(160), 512, 0, stream>>>(
      ctrl, hb, WT2, b2, yb, F_DIM, H_DIM);
  combine_k<<<dim3(T_TOK), 256, 0, stream>>>(yb, row_map, t2w, out);
}

// Round 11
// 495.287 us; speedup vs baseline: 1.0940x; 1.0104x over previous
//
#include <hip/hip_runtime.h>

// MoE top-2 of 8 experts. T=4096, H=1024, F=4096.
// router -> wave scan(128-aligned regions) -> gather(x->bf16+row_map) ->
// merged exact-grid W transpose/cvt -> grouped GEMM1(relu) -> grouped GEMM2
// -> combine gather.
// GEMM: 128x128 tile, BK=64, 4 waves, 64KB LDS => 2 blocks/CU so one block's
// MFMA covers the other's barrier/waitcnt stalls (r10: schedule-bound, all
// memory-placement levers null at 117us).
#define T_TOK 4096
#define H_DIM 1024
#define F_DIM 4096
#define E_NUM 8
#define R_TOT 8192
#define NT_MAX 72         // worst-case 128-row tiles (<= 64 + 8 partials)
#define R_CAP (NT_MAX * 128)

typedef short bf16x8 __attribute__((ext_vector_type(8)));
typedef float f32x4 __attribute__((ext_vector_type(4)));

__device__ inline unsigned short f2bf(float f) {   // RNE f32 -> bf16
  unsigned int u = __builtin_bit_cast(unsigned int, f);
  return (unsigned short)((u + 0x7FFFu + ((u >> 16) & 1u)) >> 16);
}

__device__ inline void async16(const void* g, void* l) {
  __builtin_amdgcn_global_load_lds((const __attribute__((address_space(1))) void*)g,
                                   (__attribute__((address_space(3))) void*)l, 16, 0, 0);
}

// ---------------- router ------------------------------------------------------
__global__ __launch_bounds__(256) void router_k(
    const float* __restrict__ x, const float* __restrict__ Wr,
    const float* __restrict__ br, int* __restrict__ ctrl,
    int* __restrict__ t2i, float* __restrict__ t2w) {
  int lane = threadIdx.x & 63;
  int wid  = threadIdx.x >> 6;
  int t = blockIdx.x * 4 + wid;
  const float* xr = x + (size_t)t * H_DIM;
  double acc[E_NUM];
#pragma unroll
  for (int e = 0; e < E_NUM; e++) acc[e] = 0.0;
  for (int i = lane; i < H_DIM; i += 64) {
    float xv = xr[i];
    const float* wr = Wr + (size_t)i * E_NUM;
    float4 w0 = *(const float4*)wr;
    float4 w1 = *(const float4*)(wr + 4);
    acc[0] += (double)xv * w0.x; acc[1] += (double)xv * w0.y;
    acc[2] += (double)xv * w0.z; acc[3] += (double)xv * w0.w;
    acc[4] += (double)xv * w1.x; acc[5] += (double)xv * w1.y;
    acc[6] += (double)xv * w1.z; acc[7] += (double)xv * w1.w;
  }
#pragma unroll
  for (int e = 0; e < E_NUM; e++) {
    double v = acc[e];
    for (int off = 32; off > 0; off >>= 1) v += __shfl_down(v, off);
    acc[e] = v;
  }
  if (lane == 0) {
    float l[E_NUM];
#pragma unroll
    for (int e = 0; e < E_NUM; e++) l[e] = (float)acc[e] + br[e];
    int ia = 0; float la = l[0];
#pragma unroll
    for (int e = 1; e < E_NUM; e++) if (l[e] > la) { la = l[e]; ia = e; }
    int ib = -1; float lb = -3.4e38f;
#pragma unroll
    for (int e = 0; e < E_NUM; e++) if (e != ia && l[e] > lb) { lb = l[e]; ib = e; }
    float w0 = 1.f / (1.f + __expf(lb - la));
    float w1 = 1.f - w0;
    t2i[2 * t] = ia; t2i[2 * t + 1] = ib;
    t2w[2 * t] = w0; t2w[2 * t + 1] = w1;
    atomicAdd(&ctrl[ia], 1);
    atomicAdd(&ctrl[ib], 1);
  }
}

// ------- scan (1 wave): 128-aligned offsets + tile table (<=72 tiles) ---------
__global__ void scan_k(int* ctrl) {
  int lane = threadIdx.x;     // 64 threads
  int c = (lane < 8) ? ctrl[lane] : 0;
  int tiles = (c + 127) >> 7;
  int x = tiles;
  for (int d = 1; d < 8; d <<= 1) {   // inclusive prefix over lanes 0..7
    int y = __shfl_up(x, d);
    if (lane >= d) x += y;
  }
  int excl = x - tiles;
  if (lane < 8) {
    ctrl[8 + lane]  = excl * 128;
    ctrl[17 + lane] = excl * 128;
  }
  int tot = __shfl(x, 7);
  if (lane == 0) { ctrl[25] = tot; ctrl[16] = tot * 128; }
  int ex[8], tl[8];
#pragma unroll
  for (int e = 0; e < 8; e++) { ex[e] = __shfl(excl, e); tl[e] = __shfl(tiles, e); }
  for (int i = lane; i < tot; i += 64) {
    int myE = 0;
#pragma unroll
    for (int e = 0; e < 8; e++) if (i >= ex[e] && i < ex[e] + tl[e]) myE = e;
    ctrl[32 + 2 * i] = myE;
    ctrl[33 + 2 * i] = i * 128;
  }
}

// ---------------- gather: x row -> bf16 row; row_map[token*2+slot] = row ------
__global__ __launch_bounds__(128) void gather_k(
    const float* __restrict__ x, const int* __restrict__ t2i,
    int* __restrict__ ctrl, int* __restrict__ row_map,
    unsigned short* __restrict__ xg) {
  int bid = blockIdx.x;
  __shared__ int srow;
  if (threadIdx.x == 0) {
    int e = t2i[bid];
    int row = atomicAdd(&ctrl[17 + e], 1);
    row_map[bid] = row;
    srow = row;
  }
  __syncthreads();
  int row = srow;
  int t = bid >> 1;
  const float* src = x + (size_t)t * H_DIM + threadIdx.x * 8;
  unsigned short* dst = xg + (size_t)row * H_DIM + threadIdx.x * 8;
  float4 v0 = *(const float4*)src;
  float4 v1 = *(const float4*)(src + 4);
  uint4 o;
  o.x = (unsigned int)f2bf(v0.x) | ((unsigned int)f2bf(v0.y) << 16);
  o.y = (unsigned int)f2bf(v0.z) | ((unsigned int)f2bf(v0.w) << 16);
  o.z = (unsigned int)f2bf(v1.x) | ((unsigned int)f2bf(v1.y) << 16);
  o.w = (unsigned int)f2bf(v1.z) | ((unsigned int)f2bf(v1.w) << 16);
  *(uint4*)dst = o;
}

// ------- merged transpose + fp32->bf16, exact flat grid (16384 blocks) --------
__global__ __launch_bounds__(256) void tconv_k(
    const float* __restrict__ W1, const float* __restrict__ W2,
    unsigned short* __restrict__ WT1, unsigned short* __restrict__ WT2) {
  size_t mat = (size_t)H_DIM * F_DIM;
  int bid = blockIdx.x;
  const float* in; unsigned short* out; int R, C, bx, by;
  if (bid < 8192) {
    int e = bid >> 10, t = bid & 1023;
    in = W1 + e * mat; out = WT1 + e * mat; R = H_DIM; C = F_DIM;
    bx = t & 63; by = t >> 6;
  } else {
    int e = (bid - 8192) >> 10, t = bid & 1023;
    in = W2 + e * mat; out = WT2 + e * mat; R = F_DIM; C = H_DIM;
    bx = t & 15; by = t >> 4;
  }
  int c0 = bx * 64, r0 = by * 64;
  __shared__ float tile[64][65];
  int tr = threadIdx.x >> 4, tc = threadIdx.x & 15;
#pragma unroll
  for (int p = 0; p < 4; p++) {
    int r = tr + p * 16;
    float4 v = *(const float4*)(in + (size_t)(r0 + r) * C + c0 + tc * 4);
    tile[r][tc * 4 + 0] = v.x; tile[r][tc * 4 + 1] = v.y;
    tile[r][tc * 4 + 2] = v.z; tile[r][tc * 4 + 3] = v.w;
  }
  __syncthreads();
  int cc = threadIdx.x >> 3;        // 0..31
  int r8 = (threadIdx.x & 7) * 8;   // 0..56
#pragma unroll
  for (int p = 0; p < 2; p++) {
    int c = cc + p * 32;
    uint4 o;
    o.x = (unsigned int)f2bf(tile[r8 + 0][c]) | ((unsigned int)f2bf(tile[r8 + 1][c]) << 16);
    o.y = (unsigned int)f2bf(tile[r8 + 2][c]) | ((unsigned int)f2bf(tile[r8 + 3][c]) << 16);
    o.z = (unsigned int)f2bf(tile[r8 + 4][c]) | ((unsigned int)f2bf(tile[r8 + 5][c]) << 16);
    o.w = (unsigned int)f2bf(tile[r8 + 6][c]) | ((unsigned int)f2bf(tile[r8 + 7][c]) << 16);
    *(uint4*)(out + (size_t)(c0 + c) * R + r0 + r8) = o;
  }
}

// ======= grouped BT GEMM: 128x128 tile, BK=64, 4 waves (2x2), 2 blocks/CU =====
// LDS (64KB): 2 buffers x {A[128][64] | B[128][64]} bf16, XOR-swizzled octets:
// unit(16B) = row*8 + (koct ^ (row&7)).  STG dest linear in tid (32-row chunks,
// 8 lanes/row); global source pre-swizzled within the row's 128B line.
// Loop: {16 ds_read -> lgkmcnt(0) -> BAR -> 8 STG(tile t+2 into cur buf, now
// overwrite-safe) -> 32 MFMA (setprio) -> vmcnt(8) [tile t+1 landed] -> BAR}.
// vmcnt never 0; sched_barrier fences pin the skeleton (r4/r5: load-bearing).
#define BAR() do { __builtin_amdgcn_sched_barrier(0); \
                   __builtin_amdgcn_s_barrier(); \
                   __builtin_amdgcn_sched_barrier(0); } while (0)

#define STG(gbase, kt, ebase, c) \
  async16((gbase) + (size_t)((c) * 32 + srcRow) * Kstr + (kt) + srcK8, \
          lds + (ebase) + (c) * 2048 + tid * 8)

#define LDU(ebase, row, koct) \
  (*(const bf16x8*)(lds + (ebase) + (((row) * 8 + ((koct) ^ ((row) & 7))) * 8)))

template <int MAP, bool RELU, bool OUTF32>
__global__ __launch_bounds__(256, 2) void gemm128_k(
    const int* __restrict__ ctrl, const unsigned short* __restrict__ A,
    const unsigned short* __restrict__ Bw, const float* __restrict__ bias,
    void* __restrict__ Cout, int Kstr, int N) {
  __shared__ unsigned short lds[32768];   // 64 KiB -> 2 blocks/CU
  const int bid = blockIdx.x;
  int rt, bx;
  if (MAP == 1) {       // 2304 blocks: XCD chunk q=288; rt-major (A L2-hot)
    int wg = (bid & 7) * 288 + (bid >> 3);
    rt = wg >> 5; bx = wg & 31;
  } else {              // 576 blocks: XCD chunk q=72
    int wg = (bid & 7) * 72 + (bid >> 3);
    rt = wg >> 3; bx = wg & 7;
  }
  if (rt >= ctrl[25]) return;
  const int e    = ctrl[32 + 2 * rt];
  const int row0 = ctrl[33 + 2 * rt];
  const unsigned short* Ae = A + (size_t)row0 * Kstr;
  const unsigned short* Be = Bw + (size_t)e * ((size_t)N * Kstr) + (size_t)bx * 128 * Kstr;
  const int tid = threadIdx.x, lane = tid & 63;
  const int wid = tid >> 6, wm = wid >> 1, wn = wid & 1;
  const int lr = lane & 15, klane = lane >> 4;
  const int srcRow = tid >> 3;                          // 0..31 within chunk
  const int srcK8  = ((tid & 7) ^ (srcRow & 7)) * 8;    // pre-swizzled octet
  const int NT = Kstr >> 6;

  f32x4 acc[4][4];
  f32x4 zero4 = {0.f, 0.f, 0.f, 0.f};
#pragma unroll
  for (int m = 0; m < 4; m++)
#pragma unroll
    for (int n = 0; n < 4; n++) acc[m][n] = zero4;

  // prologue: stage tile0 -> buf0, tile1 -> buf1; wait tile0; barrier
  {
    STG(Ae, 0, 0, 0); STG(Ae, 0, 0, 1); STG(Ae, 0, 0, 2); STG(Ae, 0, 0, 3);
    STG(Be, 0, 8192, 0); STG(Be, 0, 8192, 1); STG(Be, 0, 8192, 2); STG(Be, 0, 8192, 3);
    STG(Ae, 64, 16384, 0); STG(Ae, 64, 16384, 1); STG(Ae, 64, 16384, 2); STG(Ae, 64, 16384, 3);
    STG(Be, 64, 24576, 0); STG(Be, 64, 24576, 1); STG(Be, 64, 24576, 2); STG(Be, 64, 24576, 3);
    asm volatile("s_waitcnt vmcnt(8)" ::: "memory");
    BAR();
  }

  for (int t = 0; t < NT; t++) {
    const int cur = t & 1;
    const int abase = cur * 16384;
    const int bbase = abase + 8192;
    const int kt2 = min(t + 2, NT - 1) * 64;
    // ---- fragment reads (16 x ds_read_b128, conflict-free) ----
    bf16x8 a[4][2], b[4][2];
#pragma unroll
    for (int m = 0; m < 4; m++) {
      int ar = wm * 64 + m * 16 + lr;
      a[m][0] = LDU(abase, ar, klane);
      a[m][1] = LDU(abase, ar, 4 + klane);
    }
#pragma unroll
    for (int n = 0; n < 4; n++) {
      int br = wn * 64 + n * 16 + lr;
      b[n][0] = LDU(bbase, br, klane);
      b[n][1] = LDU(bbase, br, 4 + klane);
    }
    asm volatile("s_waitcnt lgkmcnt(0)" ::: "memory");
    BAR();                        // all waves done reading buf[cur]
    // ---- stage tile t+2 into buf[cur] (dead now) ----
    STG(Ae, kt2, abase, 0); STG(Ae, kt2, abase, 1);
    STG(Ae, kt2, abase, 2); STG(Ae, kt2, abase, 3);
    STG(Be, kt2, bbase, 0); STG(Be, kt2, bbase, 1);
    STG(Be, kt2, bbase, 2); STG(Be, kt2, bbase, 3);
    // ---- MFMA cluster (32) ----
    __builtin_amdgcn_s_setprio(1);
#pragma unroll
    for (int m = 0; m < 4; m++)
#pragma unroll
      for (int n = 0; n < 4; n++) {
        acc[m][n] = __builtin_amdgcn_mfma_f32_16x16x32_bf16(a[m][0], b[n][0], acc[m][n], 0, 0, 0);
        acc[m][n] = __builtin_amdgcn_mfma_f32_16x16x32_bf16(a[m][1], b[n][1], acc[m][n], 0, 0, 0);
      }
    __builtin_amdgcn_s_setprio(0);
    asm volatile("s_waitcnt vmcnt(8)" ::: "memory");   // tile t+1 landed
    BAR();
  }

  // ---------------- epilogue: plain stores -------------------------------------
  const int n0 = bx * 128;
  const float* be = bias + (size_t)e * N;
#pragma unroll
  for (int m = 0; m < 4; m++) {
#pragma unroll
    for (int q2 = 0; q2 < 4; q2++) {
      size_t ro = (size_t)(row0 + wm * 64 + m * 16 + (lane >> 4) * 4 + q2) * N;
#pragma unroll
      for (int n = 0; n < 4; n++) {
        int col = n0 + wn * 64 + n * 16 + lr;
        float v = acc[m][n][q2] + be[col];
        if (RELU) v = fmaxf(v, 0.f);
        if (OUTF32) ((float*)Cout)[ro + col] = v;
        else ((unsigned short*)Cout)[ro + col] = f2bf(v);
      }
    }
  }
}

// ---------------- combine: out[t] = w0*y[r0] + w1*y[r1] ----------------------
__global__ __launch_bounds__(256) void combine_k(
    const float* __restrict__ y, const int* __restrict__ row_map,
    const float* __restrict__ t2w, float* __restrict__ out) {
  int t = blockIdx.x;
  int i = threadIdx.x * 4;
  int r0 = row_map[2 * t], r1 = row_map[2 * t + 1];
  float w0 = t2w[2 * t], w1 = t2w[2 * t + 1];
  float4 a = *(const float4*)(y + (size_t)r0 * H_DIM + i);
  float4 b = *(const float4*)(y + (size_t)r1 * H_DIM + i);
  float4 o;
  o.x = w0 * a.x + w1 * b.x;
  o.y = w0 * a.y + w1 * b.y;
  o.z = w0 * a.z + w1 * b.z;
  o.w = w0 * a.w + w1 * b.w;
  *(float4*)(out + (size_t)t * H_DIM + i) = o;
}

extern "C" void kernel_launch(void* const* d_in, const int* in_sizes, int n_in,
                              void* d_out, int out_size, void* d_ws, size_t ws_size,
                              hipStream_t stream) {
  const float* x  = (const float*)d_in[0];
  const float* Wr = (const float*)d_in[1];
  const float* br = (const float*)d_in[2];
  const float* W1 = (const float*)d_in[3];
  const float* b1 = (const float*)d_in[4];
  const float* W2 = (const float*)d_in[5];
  const float* b2 = (const float*)d_in[6];
  float* out = (float*)d_out;

  char* ws = (char*)d_ws;
  int*   ctrl    = (int*)ws;                       // counts/offs/cursors/tile table
  int*   t2i     = (int*)(ws + 4096);
  float* t2w     = (float*)(ws + 4096 + 32768);
  int*   row_map = (int*)(ws + 4096 + 65536);      // R_TOT ints
  size_t off = (size_t)1 << 20;
  unsigned short* WT1 = (unsigned short*)(ws + off); off += (size_t)E_NUM * F_DIM * H_DIM * 2;
  unsigned short* WT2 = (unsigned short*)(ws + off); off += (size_t)E_NUM * H_DIM * F_DIM * 2;
  unsigned short* xg  = (unsigned short*)(ws + off); off += (size_t)R_CAP * H_DIM * 2;
  unsigned short* hb  = (unsigned short*)(ws + off); off += (size_t)R_CAP * F_DIM * 2;
  float*          yb  = (float*)(ws + off);          off += (size_t)R_CAP * H_DIM * 4;

  if (ws_size < off) {  // not enough scratch: fail visibly, don't corrupt memory
    hipMemsetAsync(d_out, 0, (size_t)out_size * 4, stream);
    return;
  }

  hipMemsetAsync(ctrl, 0, 4096, stream);
  hipMemsetAsync(xg, 0, (size_t)R_CAP * H_DIM * 2, stream);   // pad rows deterministic
  tconv_k<<<dim3(16384), 256, 0, stream>>>(W1, W2, WT1, WT2);
  router_k<<<dim3(T_TOK / 4), 256, 0, stream>>>(x, Wr, br, ctrl, t2i, t2w);
  scan_k<<<dim3(1), 64, 0, stream>>>(ctrl);
  gather_k<<<dim3(R_TOT), 128, 0, stream>>>(x, t2i, ctrl, row_map, xg);
  // GEMM1: hb = relu(xg @ W1 + b1), bf16   [rows x F]   72rt x 32bx = 2304
  gemm128_k<1, true, false><<<dim3(2304), 256, 0, stream>>>(
      ctrl, xg, WT1, b1, hb, H_DIM, F_DIM);
  // GEMM2: yb = hb @ W2 + b2, fp32         [rows x H]   72rt x 8bx = 576
  gemm128_k<2, false, true><<<dim3(576), 256, 0, stream>>>(
      ctrl, hb, WT2, b2, yb, F_DIM, H_DIM);
  combine_k<<<dim3(T_TOK), 256, 0, stream>>>(yb, row_map, t2w, out);
}